// Round 4
// baseline (248.959 us; speedup 1.0000x reference)
//
#include <hip/hip_runtime.h>
#include <math.h>

#define POOL 7
#define NPOS 49      // 7*7
#define CCH 256      // channels

// One wave (64 lanes) per (box, py, px) output position.
// Each lane: 4 channels as float4 -> 64 lanes x 16B = 1KB coalesced.
__global__ __launch_bounds__(256) void roialign_kernel(
    const float* __restrict__ boxes,   // [B*N, 4] (y1,x1,y2,x2)
    const float* __restrict__ meta,    // [B, 93]
    const float* __restrict__ f2,      // [B,256,256,256]
    const float* __restrict__ f3,      // [B,128,128,256]
    const float* __restrict__ f4,      // [B, 64, 64,256]
    const float* __restrict__ f5,      // [B, 32, 32,256]
    float* __restrict__ out,           // [B*N, 7, 7, 256]
    int nPos, int N)
{
    const int wave = threadIdx.x >> 6;
    const int lane = threadIdx.x & 63;
    const int pos  = blockIdx.x * 4 + wave;
    if (pos >= nPos) return;

    const int box = pos / NPOS;
    const int p   = pos - box * NPOS;
    const int py  = p / POOL;
    const int px  = p - py * POOL;
    const int b   = box / N;

    // ---- per-box scalars (wave-uniform; redundant across lanes, cheap) ----
    const float y1 = boxes[box * 4 + 0];
    const float x1 = boxes[box * 4 + 1];
    const float y2 = boxes[box * 4 + 2];
    const float x2 = boxes[box * 4 + 3];
    const float h = y2 - y1;
    const float w = x2 - x1;

    // roi_level = clip(4 + round(log2(sqrt(h*w) / (224/sqrt(area)))), 2, 5)
    const float area = meta[4] * meta[5];           // image_meta[0,4]*image_meta[0,5]
    const float cc   = 224.0f / sqrtf(area);
    const float roi  = log2f(sqrtf(h * w) / cc);
    int lvl = 4 + (int)rintf(roi);                  // rintf = round half to even, matches jnp.round
    lvl = min(max(lvl, 2), 5);

    const float* fm;
    int H;
    if      (lvl == 2) { fm = f2; H = 256; }
    else if (lvl == 3) { fm = f3; H = 128; }
    else if (lvl == 4) { fm = f4; H = 64;  }
    else               { fm = f5; H = 32;  }

    const float Hm1 = (float)(H - 1);
    // ys = y1*(H-1) + gy * ((y2-y1)*(H-1)/(ph-1))   (match reference op order)
    const float step_y = h * Hm1 / 6.0f;
    const float step_x = w * Hm1 / 6.0f;
    const float ysf = y1 * Hm1 + (float)py * step_y;
    const float xsf = x1 * Hm1 + (float)px * step_x;

    const float y0f = floorf(ysf);
    const float x0f = floorf(xsf);
    const float wy = ysf - y0f;                     // unclipped fractional weights
    const float wx = xsf - x0f;

    const int y0i = min(max((int)y0f, 0), H - 1);
    const int y1i = min((int)y0f + 1, H - 1);
    const int x0i = min(max((int)x0f, 0), H - 1);
    const int x1i = min((int)x0f + 1, H - 1);

    // ---- gather 4 neighbors, 4 channels per lane ----
    const size_t rowT = ((size_t)b * H + (size_t)y0i) * (size_t)H;
    const size_t rowB = ((size_t)b * H + (size_t)y1i) * (size_t)H;
    const size_t c0   = (size_t)lane * 4;

    const float4 tl = *(const float4*)(fm + (rowT + x0i) * CCH + c0);
    const float4 tr = *(const float4*)(fm + (rowT + x1i) * CCH + c0);
    const float4 bl = *(const float4*)(fm + (rowB + x0i) * CCH + c0);
    const float4 br = *(const float4*)(fm + (rowB + x1i) * CCH + c0);

    // top = tl + (tr-tl)*wx; bot = bl + (br-bl)*wx; res = top + (bot-top)*wy
    float4 o;
    {
        float top, bot;
        top = tl.x + (tr.x - tl.x) * wx;  bot = bl.x + (br.x - bl.x) * wx;  o.x = top + (bot - top) * wy;
        top = tl.y + (tr.y - tl.y) * wx;  bot = bl.y + (br.y - bl.y) * wx;  o.y = top + (bot - top) * wy;
        top = tl.z + (tr.z - tl.z) * wx;  bot = bl.z + (br.z - bl.z) * wx;  o.z = top + (bot - top) * wy;
        top = tl.w + (tr.w - tl.w) * wx;  bot = bl.w + (br.w - bl.w) * wx;  o.w = top + (bot - top) * wy;
    }

    *(float4*)(out + (size_t)pos * CCH + c0) = o;
}

extern "C" void kernel_launch(void* const* d_in, const int* in_sizes, int n_in,
                              void* d_out, int out_size, void* d_ws, size_t ws_size,
                              hipStream_t stream) {
    const float* boxes = (const float*)d_in[0];
    const float* meta  = (const float*)d_in[1];
    const float* f2    = (const float*)d_in[2];
    const float* f3    = (const float*)d_in[3];
    const float* f4    = (const float*)d_in[4];
    const float* f5    = (const float*)d_in[5];
    float* out = (float*)d_out;

    const int nBoxes = in_sizes[0] / 4;        // B*N = 2000
    const int B      = in_sizes[1] / 93;       // 2
    const int N      = nBoxes / B;             // 1000
    const int nPos   = nBoxes * NPOS;          // 98000

    const int blocks = (nPos + 3) / 4;         // 4 waves (positions) per block
    roialign_kernel<<<blocks, 256, 0, stream>>>(boxes, meta, f2, f3, f4, f5, out, nPos, N);
}